// Round 1
// baseline (120.513 us; speedup 1.0000x reference)
//
#include <hip/hip_runtime.h>
#include <math.h>

#define INV_SQRT2F 0.70710678118654752f

__device__ __forceinline__ float2 cmul(float2 a, float2 b) {
  return make_float2(a.x*b.x - a.y*b.y, a.x*b.y + a.y*b.x);
}
__device__ __forceinline__ float2 cmulc(float2 a, float2 b) { // a * conj(b)
  return make_float2(a.x*b.x + a.y*b.y, a.y*b.x - a.x*b.y);
}
__device__ __forceinline__ float2 cadd(float2 a, float2 b) {
  return make_float2(a.x + b.x, a.y + b.y);
}

// ---------------------------------------------------------------------------
// Kernel A: one workgroup per (b, k). Computes rho4[b][k] (16x16 complex).
//
// idx = r*1024 + c ; qubit q bit = (idx >> (19-q)) & 1.
//   r holds qubits 0..9  (bit of qubit q at r >> (9-q))
//   c holds qubits 10..19 (bit at c >> (19-q))
// psi1(r,c) = F(r) * G(c) * exp(-i/2 (b1[9] z9 z10 + b1[19] z19 z0))
//   z9 from r&1, z0 from (r>>9)&1, z10 from (c>>9)&1, z19 from c&1.
// Class p = 2*b9 + b0  ->  psi1(r,c) = F(r) * g_p(r)(c).
// psi(R,C) = sum_p Y_p(R) Ghat_p(C); Y_p = WHT(masked F); by Parseval
// Ghat Gram == g Gram, so no c-side transform needed.
// rho4[i][j] = sum_{p,p'} Cg[p][p'] * sum_L Y_p(64i+L) conj(Y_p'(64j+L)).
// ---------------------------------------------------------------------------
__global__ __launch_bounds__(1024) void iqp_rho4_kernel(
    const float* __restrict__ x,    // (B,16,4,3)
    const float* __restrict__ pw,   // (16,2)
    const float* __restrict__ lw,   // (20,2): a1,b1
    float2* __restrict__ rho4g)     // (B,4,16,16)
{
  const int k = blockIdx.x;
  const int b = blockIdx.y;
  const int t = threadIdx.x;

  __shared__ float2 sq[20][2];     // per-qubit states with a1 phase folded in
  __shared__ float2 Fm[4][1024];   // class-masked F, then in-place WHT -> Y_p
  __shared__ float  cg[32];        // 16 complex Gram accumulators
  __shared__ float  b1s[20];

  if (t < 32) cg[t] = 0.0f;
  if (t < 20) {
    const int q = t;
    const float a1 = lw[2*q];
    b1s[q] = lw[2*q + 1];
    const int p = 4*k + q/5;
    const int j = q % 5;
    float2 s0, s1;
    if (j < 4) {
      const float* xp = x + ((size_t)((b*16 + p)*4 + j))*3;
      const float hx = 0.5f*xp[0], hy = 0.5f*xp[1], hz = 0.5f*xp[2];
      const float cx = cosf(hx), sx = sinf(hx);
      const float cy = cosf(hy), sy = sinf(hy);
      const float cz = cosf(hz), sz = sinf(hz);
      float2 w0 = make_float2(cy*cx,  sy*sx);   // cy*v0 - sy*v1
      float2 w1 = make_float2(sy*cx, -cy*sx);   // sy*v0 + cy*v1
      w0 = cmul(make_float2(cz, -sz), w0);      // * exp(-i hz)
      w1 = cmul(make_float2(cz,  sz), w1);      // * exp(+i hz)
      s0 = make_float2((w0.x + w1.x)*INV_SQRT2F, (w0.y + w1.y)*INV_SQRT2F);
      s1 = make_float2((w0.x - w1.x)*INV_SQRT2F, (w0.y - w1.y)*INV_SQRT2F);
    } else {
      const float px = 0.5f*pw[2*p], py = 0.5f*pw[2*p + 1];
      const float cx = cosf(px), sx = sinf(px);
      const float cy = cosf(py), sy = sinf(py);
      const float2 w0 = make_float2(cy*cx,  sy*sx);
      const float2 w1 = make_float2(sy*cx, -cy*sx);
      s0 = make_float2((w0.x + w1.x)*INV_SQRT2F, (w0.y + w1.y)*INV_SQRT2F);
      s1 = make_float2((w0.x - w1.x)*INV_SQRT2F, (w0.y - w1.y)*INV_SQRT2F);
    }
    // fold single-qubit IQP phase exp(-i/2 a1 z): z=+1 for bit0, -1 for bit1
    const float ha = 0.5f*a1;
    const float ca = cosf(ha), sa = sinf(ha);
    sq[q][0] = cmul(s0, make_float2(ca, -sa));
    sq[q][1] = cmul(s1, make_float2(ca,  sa));
  }
  __syncthreads();

  // ---- F(r): product over qubits 0..9 + chain ZZ phases q=0..8 -----------
  {
    const int r = t;
    float2 prod = make_float2(1.f, 0.f);
    int bits[10];
    #pragma unroll
    for (int q = 0; q < 10; ++q) {
      bits[q] = (r >> (9 - q)) & 1;
      prod = cmul(prod, sq[q][bits[q]]);
    }
    float phi = 0.f;
    #pragma unroll
    for (int q = 0; q < 9; ++q) {
      const float zq  = 1.f - 2.f*(float)bits[q];
      const float zq1 = 1.f - 2.f*(float)bits[q + 1];
      phi += b1s[q]*zq*zq1;
    }
    const float hp = 0.5f*phi;
    const float2 F = cmul(prod, make_float2(cosf(hp), -sinf(hp)));
    const int pc = ((r & 1) << 1) | ((r >> 9) & 1);  // (b9, b0)
    #pragma unroll
    for (int p = 0; p < 4; ++p)
      Fm[p][r] = (p == pc) ? F : make_float2(0.f, 0.f);
  }

  // ---- G(c) and 4x4 Gram of g_p --------------------------------------------
  {
    const int c = t;
    float2 prod = make_float2(1.f, 0.f);
    int bits[10];
    #pragma unroll
    for (int q = 10; q < 20; ++q) {
      bits[q - 10] = (c >> (19 - q)) & 1;
      prod = cmul(prod, sq[q][bits[q - 10]]);
    }
    float phi = 0.f;
    #pragma unroll
    for (int q = 10; q < 19; ++q) {
      const float zq  = 1.f - 2.f*(float)bits[q - 10];
      const float zq1 = 1.f - 2.f*(float)bits[q + 1 - 10];
      phi += b1s[q]*zq*zq1;
    }
    const float hp = 0.5f*phi;
    const float2 G = cmul(prod, make_float2(cosf(hp), -sinf(hp)));
    const float mu = 1.f - 2.f*(float)((c >> 9) & 1);  // z10
    const float nu = 1.f - 2.f*(float)(c & 1);         // z19
    float2 g[4];
    #pragma unroll
    for (int p = 0; p < 4; ++p) {
      const float sp = 1.f - 2.f*(float)(p >> 1);  // sigma = z9
      const float tp = 1.f - 2.f*(float)(p & 1);   // tau   = z0
      const float ang = 0.5f*(b1s[9]*sp*mu + b1s[19]*tp*nu);
      g[p] = cmul(G, make_float2(cosf(ang), -sinf(ang)));
    }
    #pragma unroll
    for (int p = 0; p < 4; ++p)
      #pragma unroll
      for (int pp = 0; pp < 4; ++pp) {
        float2 v = cmulc(g[p], g[pp]);
        for (int off = 32; off > 0; off >>= 1) {
          v.x += __shfl_down(v.x, off);
          v.y += __shfl_down(v.y, off);
        }
        if ((t & 63) == 0) {
          atomicAdd(&cg[2*(p*4 + pp)    ], v.x);
          atomicAdd(&cg[2*(p*4 + pp) + 1], v.y);
        }
      }
  }
  __syncthreads();

  // ---- 4 in-place 1024-point normalized WHTs (rows of Fm) ----------------
  for (int d = 1; d < 1024; d <<= 1) {
    #pragma unroll
    for (int u0 = 0; u0 < 2; ++u0) {
      const int u   = t + u0*1024;
      const int row = u >> 9;
      const int bf  = u & 511;
      const int i0  = ((bf & ~(d - 1)) << 1) | (bf & (d - 1));
      const int i1  = i0 | d;
      const float2 a = Fm[row][i0];
      const float2 c = Fm[row][i1];
      Fm[row][i0] = make_float2((a.x + c.x)*INV_SQRT2F, (a.y + c.y)*INV_SQRT2F);
      Fm[row][i1] = make_float2((a.x - c.x)*INV_SQRT2F, (a.y - c.y)*INV_SQRT2F);
    }
    __syncthreads();
  }

  // ---- rho4[i][j] = sum_{L,p,p'} Cg[p][p'] Y_p(64i+L) conj(Y_p'(64j+L)) --
  float2 Cg[16];
  #pragma unroll
  for (int i = 0; i < 16; ++i) Cg[i] = make_float2(cg[2*i], cg[2*i + 1]);

  const int pair = t >> 2;          // 0..255
  const int oi = pair >> 4;         // row i of rho4
  const int oj = pair & 15;         // col j
  const int sub = t & 3;            // split of L
  float2 acc = make_float2(0.f, 0.f);
  for (int l = 0; l < 16; ++l) {
    const int L = sub*16 + l;
    float2 av[4], bv[4];
    #pragma unroll
    for (int p = 0; p < 4; ++p) {
      av[p] = Fm[p][oi*64 + L];
      bv[p] = Fm[p][oj*64 + L];
    }
    #pragma unroll
    for (int p = 0; p < 4; ++p)
      #pragma unroll
      for (int pp = 0; pp < 4; ++pp)
        acc = cadd(acc, cmul(Cg[p*4 + pp], cmulc(av[p], bv[pp])));
  }
  acc.x += __shfl_down(acc.x, 2);  acc.y += __shfl_down(acc.y, 2);
  acc.x += __shfl_down(acc.x, 1);  acc.y += __shfl_down(acc.y, 1);
  if (sub == 0)
    rho4g[((size_t)(b*4 + k)*16 + oi)*16 + oj] = acc;
}

// ---------------------------------------------------------------------------
// Kernel B: one workgroup per batch row. Partial traces, Heisenberg ops
// (closed form via XOR structure), head matmul + L2 normalize.
// ---------------------------------------------------------------------------
__device__ __forceinline__ float2 heis_M(int i, int j, float cb1, float sb1,
                                         float cb2, float sb2) {
  // M = R(beta1, XXI) @ R(beta2, IXX); nonzero at i^j in {0,3,6,5}
  const int xr = i ^ j;
  if (xr == 0) return make_float2( cb1*cb2, 0.f);
  if (xr == 3) return make_float2( 0.f,    -cb1*sb2);
  if (xr == 6) return make_float2( 0.f,    -sb1*cb2);
  if (xr == 5) return make_float2(-sb1*sb2, 0.f);
  return make_float2(0.f, 0.f);
}

__global__ __launch_bounds__(512) void iqp_head_kernel(
    const float2* __restrict__ rho4g,  // (B,4,16,16)
    const float* __restrict__ l2,      // (16,2): a2,b2
    const float* __restrict__ hw,      // (512,4)
    const float* __restrict__ hb,      // (512,)
    float* __restrict__ out)           // (B,512)
{
  const int b = blockIdx.x;
  const int t = threadIdx.x;

  __shared__ float2 l0[256], l1[256], l3[256];
  __shared__ float2 r012[64], r123[64], rk0[64], rk3[64];
  __shared__ float2 r01[16], r23[16], q0[4], q3[4];
  __shared__ float e[4];
  __shared__ float wsum[8];
  __shared__ float nrm;

  if (t < 256) {
    l0[t] = rho4g[(size_t)(b*4 + 0)*256 + t];
    l1[t] = rho4g[(size_t)(b*4 + 1)*256 + t];
    l3[t] = rho4g[(size_t)(b*4 + 3)*256 + t];
  }
  __syncthreads();

  if (t < 64) {
    const int i = t >> 3, j = t & 7;
    // trace out qubit 3 (LSB):  rho012[i][j] = sum_x rho4[2i+x][2j+x]
    r012[t] = cadd(l0[(2*i)*16 + 2*j], l0[(2*i + 1)*16 + 2*j + 1]);
    // trace out qubit 0 (MSB):  rho123[i][j] = sum_x rho4[8x+i][8x+j]
    r123[t] = cadd(l0[i*16 + j], l0[(i + 8)*16 + (j + 8)]);
  }
  if (t < 16) {
    const int i = t >> 2, j = t & 3;
    float2 s1 = make_float2(0.f, 0.f), s2 = make_float2(0.f, 0.f);
    for (int w = 0; w < 4; ++w) {
      s1 = cadd(s1, l0[(4*i + w)*16 + 4*j + w]);  // rho01 (keep qubits 0,1)
      s2 = cadd(s2, l0[(4*w + i)*16 + 4*w + j]);  // rho23 (keep qubits 2,3)
    }
    r01[t] = s1;  r23[t] = s2;
  }
  if (t < 4) {
    const int i = t >> 1, j = t & 1;
    float2 s1 = make_float2(0.f, 0.f), s2 = make_float2(0.f, 0.f);
    for (int w = 0; w < 8; ++w) {
      s1 = cadd(s1, l1[(8*i + w)*16 + 8*j + w]);      // rho_q0, block 1
      s2 = cadd(s2, l3[(2*w + i)*16 + 2*w + j]);      // rho_q3, block 3
    }
    q0[t] = s1;  q3[t] = s2;
  }
  __syncthreads();

  if (t < 64) {
    const int i = t >> 3, j = t & 7;
    // rho_k0 = kron(q3, r01);  rho_k3 = kron(r23, q0)
    rk0[t] = cmul(q3[(i >> 2)*2 + (j >> 2)], r01[(i & 3)*4 + (j & 3)]);
    rk3[t] = cmul(r23[(i >> 1)*4 + (j >> 1)], q0[(i & 1)*2 + (j & 1)]);
  }
  __syncthreads();

  if (t < 256) {
    const int k = t >> 6;             // one wave per k
    const int idx = t & 63;
    const int i = idx >> 3, j = idx & 7;
    const float alpha = l2[2*k];
    const float beta1 = l2[2*((k + 15) & 15) + 1];
    const float beta2 = l2[2*k + 1];
    const float ca = cosf(alpha), sa = sinf(alpha);
    const float cb1 = cosf(beta1), sb1 = sinf(beta1);
    const float cb2 = cosf(beta2), sb2 = sinf(beta2);
    const float2 m1 = heis_M(i,     j, cb1, sb1, cb2, sb2);
    const float2 m2 = heis_M(i ^ 2, j, cb1, sb1, cb2, sb2);
    // N = ca*m1 - i*sa*m2 ; O = IZI*N (row sign from middle bit of i)
    float2 O = make_float2(ca*m1.x + sa*m2.y, ca*m1.y - sa*m2.x);
    if ((i >> 1) & 1) { O.x = -O.x; O.y = -O.y; }
    const float2* rho = (k == 0) ? rk0 : (k == 1) ? r012 : (k == 2) ? r123 : rk3;
    const float2 rv = rho[j*8 + i];
    float contrib = O.x*rv.x - O.y*rv.y;  // Re(O[i][j] * rho[j][i])
    for (int off = 32; off > 0; off >>= 1) contrib += __shfl_down(contrib, off);
    if (idx == 0) e[k] = contrib;
  }
  __syncthreads();

  // head: out[b][o] = sum_k e[k]*hw[o][k] + hb[o]; then L2-normalize row
  const float val = hb[t] + e[0]*hw[4*t] + e[1]*hw[4*t + 1]
                  + e[2]*hw[4*t + 2] + e[3]*hw[4*t + 3];
  float ss = val*val;
  for (int off = 32; off > 0; off >>= 1) ss += __shfl_down(ss, off);
  if ((t & 63) == 0) wsum[t >> 6] = ss;
  __syncthreads();
  if (t == 0) {
    float s = 0.f;
    for (int w = 0; w < 8; ++w) s += wsum[w];
    nrm = fmaxf(sqrtf(s), 1e-12f);
  }
  __syncthreads();
  out[(size_t)b*512 + t] = val / nrm;
}

extern "C" void kernel_launch(void* const* d_in, const int* in_sizes, int n_in,
                              void* d_out, int out_size, void* d_ws, size_t ws_size,
                              hipStream_t stream) {
  const float* x  = (const float*)d_in[0];  // (B,16,4,3)
  const float* pw = (const float*)d_in[1];  // (16,2)
  const float* lw = (const float*)d_in[2];  // (20,2)
  const float* l2 = (const float*)d_in[3];  // (16,2)
  const float* hw = (const float*)d_in[4];  // (512,4)
  const float* hb = (const float*)d_in[5];  // (512,)
  const int B = in_sizes[0] / (16*4*3);

  float2* rho4g = (float2*)d_ws;            // B*4*256 complex = 64 KB for B=8

  iqp_rho4_kernel<<<dim3(4, B), 1024, 0, stream>>>(x, pw, lw, rho4g);
  iqp_head_kernel<<<B, 512, 0, stream>>>(rho4g, l2, hw, hb, (float*)d_out);
}

// Round 2
// 76.156 us; speedup vs baseline: 1.5825x; 1.5825x over previous
//
#include <hip/hip_runtime.h>
#include <math.h>

#define INV_SQRT2F 0.70710678118654752f

__device__ __forceinline__ float2 cmul(float2 a, float2 b) {
  return make_float2(a.x*b.x - a.y*b.y, a.x*b.y + a.y*b.x);
}
__device__ __forceinline__ float2 cmulc(float2 a, float2 b) { // a * conj(b)
  return make_float2(a.x*b.x + a.y*b.y, a.y*b.x - a.x*b.y);
}
__device__ __forceinline__ float2 cadd(float2 a, float2 b) {
  return make_float2(a.x + b.x, a.y + b.y);
}

// ---------------------------------------------------------------------------
// Fully fused kernel: one workgroup per batch row b. 1024 threads.
//
// Math (validated structure from R1, further reduced):
//  idx = r*1024 + c. Class p = (b9<<1)|b0 from r's edge bits (r&1, r>>9).
//  psi1(r,c) = F(r) * g_p(c). After H^20: psi(R,C) = sum_p Y_p(R) Ghat_p(C).
//  Y_p(R) = (1/2) * (-1)^{(L&1)b9(p)} (-1)^{(i>>3)b0(p)} * What_p[mid(R)]
//    where What_p = 256-pt normalized WHT of F restricted to class p over
//    the middle 8 bits m (r = (b0<<9)|(m<<1)|b9), i=R>>6, L=R&63,
//    mid(R) = 32*(i&7) + (L>>1).
//  rho4[i][j] = sum_{p,p'} Cg[p][p'] * sum_L Y_p(64i+L) conj(Y_p'(64j+L)).
//  Summing L's LSB kills pairs with b9(p)!=b9(p') -> 8 pairs survive:
//  rho4[i][j] = 0.5 * sum_{same-b9 pairs} Cg[pp'] (-1)^{(i>>3)(p&1)}
//               (-1)^{(j>>3)(p'&1)} D_{pp'}[i&7][j&7],
//    D_{pp'}[x][y] = sum_{u<32} What_p[32x+u] conj(What_p'[32y+u]).
//  Cg closed form (|G(c)|^2 telescopes to 1 per qubit):
//    Cg[p][p] = 1;  Cg[0][1] = Cg[2][3] = gamma,  gamma =
//    s19[0] e^{-i b1[19]} + s19[1] e^{+i b1[19]},  s19[mu]=|sq19[mu]|^2.
// ---------------------------------------------------------------------------
__global__ __launch_bounds__(1024) void iqp_fused_kernel(
    const float* __restrict__ x,    // (B,16,4,3)
    const float* __restrict__ pw,   // (16,2)
    const float* __restrict__ lw,   // (20,2): a1,b1
    const float* __restrict__ l2,   // (16,2): a2,b2
    const float* __restrict__ hw,   // (512,4)
    const float* __restrict__ hb,   // (512,)
    float* __restrict__ out)        // (B,512)
{
  const int b = blockIdx.x;
  const int t = threadIdx.x;
  const int lane = t & 63;

  __shared__ float2 sqs[4][20][2];   // per-k single-qubit states (a1 folded)
  __shared__ float  b1s[20];
  __shared__ float2 W[4][4][8][33];  // [k][class p][chunk x][u] padded pitch
  __shared__ float2 D[4][8][64];     // [k][pair][x*8+y]
  __shared__ float2 rho[4][256];     // rho4 per k, row-major 16x16
  __shared__ float2 r012[64], r123[64], rk0[64], rk3[64];
  __shared__ float2 r01[16], r23[16], q0s[4], q3s[4];
  __shared__ float  e[4];
  __shared__ float  wsum[8];
  __shared__ float  nrm;

  // ---- phase 0: single-qubit states for all 4 blocks ---------------------
  if (t < 80) {
    const int k2 = t / 20, q = t % 20;
    const int pch = 4*k2 + q/5;
    const int j = q % 5;
    float2 s0, s1;
    if (j < 4) {
      const float* xp = x + ((size_t)((b*16 + pch)*4 + j))*3;
      const float hx = 0.5f*xp[0], hy = 0.5f*xp[1], hz = 0.5f*xp[2];
      const float cx = cosf(hx), sx = sinf(hx);
      const float cy = cosf(hy), sy = sinf(hy);
      const float cz = cosf(hz), sz = sinf(hz);
      float2 w0 = make_float2(cy*cx,  sy*sx);
      float2 w1 = make_float2(sy*cx, -cy*sx);
      w0 = cmul(make_float2(cz, -sz), w0);
      w1 = cmul(make_float2(cz,  sz), w1);
      s0 = make_float2((w0.x + w1.x)*INV_SQRT2F, (w0.y + w1.y)*INV_SQRT2F);
      s1 = make_float2((w0.x - w1.x)*INV_SQRT2F, (w0.y - w1.y)*INV_SQRT2F);
    } else {
      const float px = 0.5f*pw[2*pch], py = 0.5f*pw[2*pch + 1];
      const float cx = cosf(px), sx = sinf(px);
      const float cy = cosf(py), sy = sinf(py);
      const float2 w0 = make_float2(cy*cx,  sy*sx);
      const float2 w1 = make_float2(sy*cx, -cy*sx);
      s0 = make_float2((w0.x + w1.x)*INV_SQRT2F, (w0.y + w1.y)*INV_SQRT2F);
      s1 = make_float2((w0.x - w1.x)*INV_SQRT2F, (w0.y - w1.y)*INV_SQRT2F);
    }
    const float ha = 0.5f*lw[2*q];
    const float ca = cosf(ha), sa = sinf(ha);
    sqs[k2][q][0] = cmul(s0, make_float2(ca, -sa));
    sqs[k2][q][1] = cmul(s1, make_float2(ca,  sa));
    if (k2 == 0) b1s[q] = lw[2*q + 1];
  }
  __syncthreads();

  const int kk = t >> 8;         // which block k this wave-group handles
  const int cls = (t >> 6) & 3;  // class p for this wave

  // ---- phase 1: F on class cls + in-wave 256-pt register WHT -------------
  {
    const int b0 = cls & 1, b9 = cls >> 1;
    float2 v[4];
    #pragma unroll
    for (int j = 0; j < 4; ++j) {
      const int m = j*64 + lane;
      const int r = (b0 << 9) | (m << 1) | b9;
      float2 prod = make_float2(1.f, 0.f);
      int bits[10];
      #pragma unroll
      for (int q = 0; q < 10; ++q) {
        bits[q] = (r >> (9 - q)) & 1;
        prod = cmul(prod, sqs[kk][q][bits[q]]);
      }
      float phi = 0.f;
      #pragma unroll
      for (int q = 0; q < 9; ++q) {
        const float zq  = 1.f - 2.f*(float)bits[q];
        const float zq1 = 1.f - 2.f*(float)bits[q + 1];
        phi += b1s[q]*zq*zq1;
      }
      const float hp = 0.5f*phi;
      v[j] = cmul(prod, make_float2(cosf(hp), -sinf(hp)));
    }
    // register stages over m bits 6,7 (unnormalized)
    {
      float2 a0 = v[0], a2 = v[2];
      v[0] = cadd(a0, a2); v[2] = make_float2(a0.x - a2.x, a0.y - a2.y);
      float2 a1 = v[1], a3 = v[3];
      v[1] = cadd(a1, a3); v[3] = make_float2(a1.x - a3.x, a1.y - a3.y);
      a0 = v[0]; a1 = v[1];
      v[0] = cadd(a0, a1); v[1] = make_float2(a0.x - a1.x, a0.y - a1.y);
      a2 = v[2]; a3 = v[3];
      v[2] = cadd(a2, a3); v[3] = make_float2(a2.x - a3.x, a2.y - a3.y);
    }
    // lane stages over m bits 0..5 via shfl_xor (unnormalized)
    #pragma unroll
    for (int mask = 1; mask <= 32; mask <<= 1) {
      #pragma unroll
      for (int j = 0; j < 4; ++j) {
        const float px = __shfl_xor(v[j].x, mask);
        const float py = __shfl_xor(v[j].y, mask);
        if (lane & mask) v[j] = make_float2(px - v[j].x, py - v[j].y);
        else             v[j] = make_float2(v[j].x + px, v[j].y + py);
      }
    }
    // scale by 2^-4 (8 normalized stages) and store
    #pragma unroll
    for (int j = 0; j < 4; ++j) {
      const int m = j*64 + lane;
      W[kk][cls][m >> 5][m & 31] =
          make_float2(v[j].x*0.0625f, v[j].y*0.0625f);
    }
  }
  __syncthreads();

  // ---- phase 2: D chunk-Grams (2048 outputs, 2 per thread) ---------------
  #pragma unroll
  for (int rep = 0; rep < 2; ++rep) {
    const int o = t + rep*1024;
    const int dk = o >> 9, rem = o & 511;
    const int pr = rem >> 6, xx = (rem >> 3) & 7, yy = rem & 7;
    const int pa = pr >> 1;
    const int pb = (pr & 1) + ((pr >> 2) << 1);
    float2 acc = make_float2(0.f, 0.f);
    #pragma unroll 8
    for (int u = 0; u < 32; ++u)
      acc = cadd(acc, cmulc(W[dk][pa][xx][u], W[dk][pb][yy][u]));
    D[dk][pr][xx*8 + yy] = acc;
  }
  __syncthreads();

  // ---- phase 3: assemble rho4 (1 output per thread) ----------------------
  {
    const int dk = t >> 8, ij = t & 255;
    const int i = ij >> 4, j = ij & 15;
    const int xy = (i & 7)*8 + (j & 7);
    const int si = i >> 3, sj = j >> 3;
    const float2 q19a = sqs[dk][19][0], q19b = sqs[dk][19][1];
    const float s19a = q19a.x*q19a.x + q19a.y*q19a.y;
    const float s19b = q19b.x*q19b.x + q19b.y*q19b.y;
    const float b119 = b1s[19];
    const float cb = cosf(b119), sb = sinf(b119);
    const float2 gam = make_float2((s19a + s19b)*cb, (s19b - s19a)*sb);
    float2 acc = cadd(D[dk][0][xy], D[dk][4][xy]);             // (0,0)+(2,2)
    {
      const float2 t2 = cadd(D[dk][3][xy], D[dk][7][xy]);      // (1,1)+(3,3)
      const float sg = ((si ^ sj) & 1) ? -1.f : 1.f;
      acc.x += sg*t2.x; acc.y += sg*t2.y;
    }
    {
      float2 t3 = cadd(D[dk][1][xy], D[dk][5][xy]);            // (0,1)+(2,3)
      t3 = cmul(gam, t3);
      const float sg = (sj & 1) ? -1.f : 1.f;
      acc.x += sg*t3.x; acc.y += sg*t3.y;
    }
    {
      float2 t4 = cadd(D[dk][2][xy], D[dk][6][xy]);            // (1,0)+(3,2)
      t4 = cmulc(t4, gam);                                     // * conj(gamma)
      const float sg = (si & 1) ? -1.f : 1.f;
      acc.x += sg*t4.x; acc.y += sg*t4.y;
    }
    rho[dk][ij] = make_float2(0.5f*acc.x, 0.5f*acc.y);
  }
  __syncthreads();

  // ---- phase 4: partial traces -------------------------------------------
  if (t < 64) {
    const int i = t >> 3, j = t & 7;
    r012[t] = cadd(rho[0][(2*i)*16 + 2*j], rho[0][(2*i + 1)*16 + 2*j + 1]);
    r123[t] = cadd(rho[0][i*16 + j], rho[0][(i + 8)*16 + (j + 8)]);
  }
  if (t < 16) {
    const int i = t >> 2, j = t & 3;
    float2 s1 = make_float2(0.f, 0.f), s2 = make_float2(0.f, 0.f);
    for (int w = 0; w < 4; ++w) {
      s1 = cadd(s1, rho[0][(4*i + w)*16 + 4*j + w]);
      s2 = cadd(s2, rho[0][(4*w + i)*16 + 4*w + j]);
    }
    r01[t] = s1;  r23[t] = s2;
  }
  if (t < 4) {
    const int i = t >> 1, j = t & 1;
    float2 s1 = make_float2(0.f, 0.f), s2 = make_float2(0.f, 0.f);
    for (int w = 0; w < 8; ++w) {
      s1 = cadd(s1, rho[1][(8*i + w)*16 + 8*j + w]);
      s2 = cadd(s2, rho[3][(2*w + i)*16 + 2*w + j]);
    }
    q0s[t] = s1;  q3s[t] = s2;
  }
  __syncthreads();

  if (t < 64) {
    const int i = t >> 3, j = t & 7;
    rk0[t] = cmul(q3s[(i >> 2)*2 + (j >> 2)], r01[(i & 3)*4 + (j & 3)]);
    rk3[t] = cmul(r23[(i >> 1)*4 + (j >> 1)], q0s[(i & 1)*2 + (j & 1)]);
  }
  __syncthreads();

  // ---- phase 5: Heisenberg expectations ----------------------------------
  if (t < 256) {
    const int k = t >> 6;
    const int idx = t & 63;
    const int i = idx >> 3, j = idx & 7;
    const float alpha = l2[2*k];
    const float beta1 = l2[2*((k + 15) & 15) + 1];
    const float beta2 = l2[2*k + 1];
    const float ca = cosf(alpha), sa = sinf(alpha);
    const float cb1 = cosf(beta1), sb1 = sinf(beta1);
    const float cb2 = cosf(beta2), sb2 = sinf(beta2);
    float2 m1, m2;
    {
      const int xr = i ^ j;
      m1 = (xr == 0) ? make_float2( cb1*cb2, 0.f)
         : (xr == 3) ? make_float2( 0.f,    -cb1*sb2)
         : (xr == 6) ? make_float2( 0.f,    -sb1*cb2)
         : (xr == 5) ? make_float2(-sb1*sb2, 0.f)
         : make_float2(0.f, 0.f);
      const int xr2 = xr ^ 2;
      m2 = (xr2 == 0) ? make_float2( cb1*cb2, 0.f)
         : (xr2 == 3) ? make_float2( 0.f,    -cb1*sb2)
         : (xr2 == 6) ? make_float2( 0.f,    -sb1*cb2)
         : (xr2 == 5) ? make_float2(-sb1*sb2, 0.f)
         : make_float2(0.f, 0.f);
    }
    float2 O = make_float2(ca*m1.x + sa*m2.y, ca*m1.y - sa*m2.x);
    if ((i >> 1) & 1) { O.x = -O.x; O.y = -O.y; }
    const float2* rp = (k == 0) ? rk0 : (k == 1) ? r012 : (k == 2) ? r123 : rk3;
    const float2 rv = rp[j*8 + i];
    float contrib = O.x*rv.x - O.y*rv.y;
    for (int off = 32; off > 0; off >>= 1) contrib += __shfl_down(contrib, off);
    if (idx == 0) e[k] = contrib;
  }
  __syncthreads();

  // ---- phase 6: head + L2 normalize --------------------------------------
  float val = 0.f;
  if (t < 512) {
    val = hb[t] + e[0]*hw[4*t] + e[1]*hw[4*t + 1]
        + e[2]*hw[4*t + 2] + e[3]*hw[4*t + 3];
    float ss = val*val;
    for (int off = 32; off > 0; off >>= 1) ss += __shfl_down(ss, off);
    if ((t & 63) == 0) wsum[t >> 6] = ss;
  }
  __syncthreads();
  if (t == 0) {
    float s = 0.f;
    for (int w = 0; w < 8; ++w) s += wsum[w];
    nrm = fmaxf(sqrtf(s), 1e-12f);
  }
  __syncthreads();
  if (t < 512) out[(size_t)b*512 + t] = val / nrm;
}

extern "C" void kernel_launch(void* const* d_in, const int* in_sizes, int n_in,
                              void* d_out, int out_size, void* d_ws, size_t ws_size,
                              hipStream_t stream) {
  const float* x  = (const float*)d_in[0];  // (B,16,4,3)
  const float* pw = (const float*)d_in[1];  // (16,2)
  const float* lw = (const float*)d_in[2];  // (20,2)
  const float* l2 = (const float*)d_in[3];  // (16,2)
  const float* hw = (const float*)d_in[4];  // (512,4)
  const float* hb = (const float*)d_in[5];  // (512,)
  const int B = in_sizes[0] / (16*4*3);

  iqp_fused_kernel<<<B, 1024, 0, stream>>>(x, pw, lw, l2, hw, hb, (float*)d_out);
}

// Round 4
// 69.962 us; speedup vs baseline: 1.7225x; 1.0885x over previous
//
#include <hip/hip_runtime.h>
#include <math.h>

#define INV_SQRT2F 0.70710678118654752f

__device__ __forceinline__ float2 cmul(float2 a, float2 b) {
  return make_float2(a.x*b.x - a.y*b.y, a.x*b.y + a.y*b.x);
}
__device__ __forceinline__ float2 cmulc(float2 a, float2 b) { // a * conj(b)
  return make_float2(a.x*b.x + a.y*b.y, a.y*b.x - a.x*b.y);
}
__device__ __forceinline__ float2 cadd(float2 a, float2 b) {
  return make_float2(a.x + b.x, a.y + b.y);
}

// ---------------------------------------------------------------------------
// Fully fused kernel, one workgroup per batch row b, 1024 threads.
//
// R2-verified math, plus:
//  * block k=2 never used -> dropped.
//  * block k=1 only enters via rho_q0 = signed combo of pair TRACES of D;
//    tr(D_{pp'}) = <F_p, F_p'> by Parseval (NORMALIZED WHT) -> no WHT, no
//    Gram; store F UNSCALED (R3 bug: scaling by 1/16 without the WHT made
//    these inner products 256x too small).
//  * block k=3 only enters via rho_q3 = partial diagonal sums of D where
//    gamma cross-class terms cancel (v2-parity); factor works out to 1.
// Blocks indexed kidx: 0->k0, 1->k1, 2->k3.
// ---------------------------------------------------------------------------
__global__ __launch_bounds__(1024) void iqp_fused_kernel(
    const float* __restrict__ x,    // (B,16,4,3)
    const float* __restrict__ pw,   // (16,2)
    const float* __restrict__ lw,   // (20,2): a1,b1
    const float* __restrict__ l2,   // (16,2): a2,b2
    const float* __restrict__ hw,   // (512,4)
    const float* __restrict__ hb,   // (512,)
    float* __restrict__ out)        // (B,512)
{
  const int b = blockIdx.x;
  const int t = threadIdx.x;
  const int lane = t & 63;
  const int wid = t >> 6;

  __shared__ float2 sqs[3][20][2];   // per-kidx single-qubit states (a1 folded)
  __shared__ float  b1s[20];
  __shared__ float2 W[3][4][8][33];  // [kidx][class][chunk x][u], padded pitch
  __shared__ float2 D0[8][64];       // block-0 chunk Grams [pair][x*8+y]
  __shared__ float2 ipv[6];          // block-1 ips: 00,11,22,33,01,23
  __shared__ float2 q3part[4][3];    // block-3 per-class partials: 00,01,11
  __shared__ float2 rho[256];        // rho4 block 0
  __shared__ float2 r012[64], r123[64], rk0[64], rk3[64];
  __shared__ float2 r01[16], r23[16], q0s[4], q3s[4];
  __shared__ float  e[4];
  __shared__ float  wsum[8];
  __shared__ float  nrm;

  // ---- phase 0: single-qubit states for blocks {0,1,3} -------------------
  if (t < 60) {
    const int kidx = t / 20, q = t % 20;
    const int k = (kidx == 2) ? 3 : kidx;
    const int pch = 4*k + q/5;
    const int j = q % 5;
    float2 s0, s1;
    if (j < 4) {
      const float* xp = x + ((size_t)((b*16 + pch)*4 + j))*3;
      float cx, sx, cy, sy, cz, sz;
      __sincosf(0.5f*xp[0], &sx, &cx);
      __sincosf(0.5f*xp[1], &sy, &cy);
      __sincosf(0.5f*xp[2], &sz, &cz);
      float2 w0 = make_float2(cy*cx,  sy*sx);
      float2 w1 = make_float2(sy*cx, -cy*sx);
      w0 = cmul(make_float2(cz, -sz), w0);
      w1 = cmul(make_float2(cz,  sz), w1);
      s0 = make_float2((w0.x + w1.x)*INV_SQRT2F, (w0.y + w1.y)*INV_SQRT2F);
      s1 = make_float2((w0.x - w1.x)*INV_SQRT2F, (w0.y - w1.y)*INV_SQRT2F);
    } else {
      float cx, sx, cy, sy;
      __sincosf(0.5f*pw[2*pch], &sx, &cx);
      __sincosf(0.5f*pw[2*pch + 1], &sy, &cy);
      const float2 w0 = make_float2(cy*cx,  sy*sx);
      const float2 w1 = make_float2(sy*cx, -cy*sx);
      s0 = make_float2((w0.x + w1.x)*INV_SQRT2F, (w0.y + w1.y)*INV_SQRT2F);
      s1 = make_float2((w0.x - w1.x)*INV_SQRT2F, (w0.y - w1.y)*INV_SQRT2F);
    }
    float ca, sa;
    __sincosf(0.5f*lw[2*q], &sa, &ca);
    sqs[kidx][q][0] = cmul(s0, make_float2(ca, -sa));
    sqs[kidx][q][1] = cmul(s1, make_float2(ca,  sa));
    if (kidx == 0) b1s[q] = lw[2*q + 1];
  }
  __syncthreads();

  // ---- phase 1: F per (kidx, class) wave; WHT except for kidx==1 ---------
  if (wid < 12) {
    const int kk = wid >> 2;       // kidx
    const int cls = wid & 3;
    const int b0 = cls & 1, b9 = cls >> 1;
    float2 v[4];
    #pragma unroll
    for (int j = 0; j < 4; ++j) {
      const int m = j*64 + lane;
      const int r = (b0 << 9) | (m << 1) | b9;
      float2 prod = make_float2(1.f, 0.f);
      int bits[10];
      #pragma unroll
      for (int q = 0; q < 10; ++q) {
        bits[q] = (r >> (9 - q)) & 1;
        prod = cmul(prod, sqs[kk][q][bits[q]]);
      }
      float phi = 0.f;
      #pragma unroll
      for (int q = 0; q < 9; ++q) {
        const float zq  = 1.f - 2.f*(float)bits[q];
        const float zq1 = 1.f - 2.f*(float)bits[q + 1];
        phi += b1s[q]*zq*zq1;
      }
      float sp, cp;
      __sincosf(0.5f*phi, &sp, &cp);
      v[j] = cmul(prod, make_float2(cp, -sp));
    }
    if (kk != 1) {  // WHT (block 1 only needs Parseval-invariant ips)
      {
        float2 a0 = v[0], a2 = v[2];
        v[0] = cadd(a0, a2); v[2] = make_float2(a0.x - a2.x, a0.y - a2.y);
        float2 a1 = v[1], a3 = v[3];
        v[1] = cadd(a1, a3); v[3] = make_float2(a1.x - a3.x, a1.y - a3.y);
        a0 = v[0]; a1 = v[1];
        v[0] = cadd(a0, a1); v[1] = make_float2(a0.x - a1.x, a0.y - a1.y);
        a2 = v[2]; a3 = v[3];
        v[2] = cadd(a2, a3); v[3] = make_float2(a2.x - a3.x, a2.y - a3.y);
      }
      #pragma unroll
      for (int mask = 1; mask <= 32; mask <<= 1) {
        #pragma unroll
        for (int j = 0; j < 4; ++j) {
          const float px = __shfl_xor(v[j].x, mask);
          const float py = __shfl_xor(v[j].y, mask);
          if (lane & mask) v[j] = make_float2(px - v[j].x, py - v[j].y);
          else             v[j] = make_float2(v[j].x + px, v[j].y + py);
        }
      }
    }
    // normalized-WHT scale (8 stages -> 2^-4) ONLY where the WHT ran;
    // block 1 stores raw F so <F,F> comes out unscaled (Parseval).
    const float scl = (kk == 1) ? 1.0f : 0.0625f;
    #pragma unroll
    for (int j = 0; j < 4; ++j) {
      const int m = j*64 + lane;
      W[kk][cls][m >> 5][m & 31] =
          make_float2(v[j].x*scl, v[j].y*scl);
    }
  }
  __syncthreads();

  // ---- phase 2: contractions ---------------------------------------------
  if (wid < 8) {
    // block 0: full chunk-Gram, 512 outputs, 1 per thread
    const int pr = t >> 6, idx = t & 63, xx = idx >> 3, yy = idx & 7;
    const int pa = pr >> 1;
    const int pb = (pr & 1) + ((pr >> 2) << 1);
    float2 acc = make_float2(0.f, 0.f);
    #pragma unroll 8
    for (int u = 0; u < 32; ++u)
      acc = cadd(acc, cmulc(W[0][pa][xx][u], W[0][pb][yy][u]));
    D0[pr][xx*8 + yy] = acc;
  } else if (wid < 12) {
    // block 1: inner products <F_pa, F_pb> over all 256 entries
    const int w4 = wid - 8;
    const int prl[6][2] = {{0,0},{1,1},{2,2},{3,3},{0,1},{2,3}};
    #pragma unroll
    for (int rep = 0; rep < 2; ++rep) {
      const int which = (rep == 0) ? w4 : w4 + 4;
      if (rep == 1 && w4 >= 2) break;
      const int pa = prl[which][0], pb = prl[which][1];
      float2 acc = make_float2(0.f, 0.f);
      #pragma unroll
      for (int jj = 0; jj < 4; ++jj) {
        const int m = jj*64 + lane;
        acc = cadd(acc, cmulc(W[1][pa][m >> 5][m & 31],
                              W[1][pb][m >> 5][m & 31]));
      }
      for (int off = 32; off > 0; off >>= 1) {
        acc.x += __shfl_down(acc.x, off);
        acc.y += __shfl_down(acc.y, off);
      }
      if (lane == 0) ipv[which] = acc;
    }
  } else {
    // block 3 (kidx 2): partial diagonal strips of diagonal pairs D_cc
    const int c = wid - 12;
    const int lo = lane >> 4;
    const int u0 = (lane & 15)*2;
    float2 a00 = make_float2(0.f, 0.f), a01 = a00, a11 = a00;
    #pragma unroll
    for (int du = 0; du < 2; ++du) {
      const float2 p0 = W[2][c][(lo << 1)    ][u0 + du];
      const float2 p1 = W[2][c][(lo << 1) | 1][u0 + du];
      a00 = cadd(a00, cmulc(p0, p0));
      a01 = cadd(a01, cmulc(p0, p1));
      a11 = cadd(a11, cmulc(p1, p1));
    }
    for (int off = 32; off > 0; off >>= 1) {
      a00.x += __shfl_down(a00.x, off); a00.y += __shfl_down(a00.y, off);
      a01.x += __shfl_down(a01.x, off); a01.y += __shfl_down(a01.y, off);
      a11.x += __shfl_down(a11.x, off); a11.y += __shfl_down(a11.y, off);
    }
    if (lane == 0) {
      q3part[c][0] = a00; q3part[c][1] = a01; q3part[c][2] = a11;
    }
  }
  __syncthreads();

  // ---- phase 3: assemble rho (block 0), q0 (block 1), q3 (block 3) -------
  if (t < 256) {
    const int i = t >> 4, j = t & 15;
    const int xy = (i & 7)*8 + (j & 7);
    const int si = i >> 3, sj = j >> 3;
    const float2 q19a = sqs[0][19][0], q19b = sqs[0][19][1];
    const float s19a = q19a.x*q19a.x + q19a.y*q19a.y;
    const float s19b = q19b.x*q19b.x + q19b.y*q19b.y;
    const float cb = __cosf(b1s[19]), sb = __sinf(b1s[19]);
    const float2 gam = make_float2((s19a + s19b)*cb, (s19b - s19a)*sb);
    float2 acc = cadd(D0[0][xy], D0[4][xy]);                 // (0,0)+(2,2)
    {
      const float2 t2 = cadd(D0[3][xy], D0[7][xy]);          // (1,1)+(3,3)
      const float sg = ((si ^ sj) & 1) ? -1.f : 1.f;
      acc.x += sg*t2.x; acc.y += sg*t2.y;
    }
    {
      float2 t3 = cadd(D0[1][xy], D0[5][xy]);                // (0,1)+(2,3)
      t3 = cmul(gam, t3);
      const float sg = (sj & 1) ? -1.f : 1.f;
      acc.x += sg*t3.x; acc.y += sg*t3.y;
    }
    {
      float2 t4 = cadd(D0[2][xy], D0[6][xy]);                // (1,0)+(3,2)
      t4 = cmulc(t4, gam);
      const float sg = (si & 1) ? -1.f : 1.f;
      acc.x += sg*t4.x; acc.y += sg*t4.y;
    }
    rho[t] = make_float2(0.5f*acc.x, 0.5f*acc.y);
  } else if (t < 260) {
    // q0[p][q] = 0.5( T04 + (-1)^{p^q} T37 + (-1)^q gam1 T15
    //                 + (-1)^p conj(gam1 T15) )
    const int pp = (t - 256) >> 1, qq = (t - 256) & 1;
    const float2 q19a = sqs[1][19][0], q19b = sqs[1][19][1];
    const float s19a = q19a.x*q19a.x + q19a.y*q19a.y;
    const float s19b = q19b.x*q19b.x + q19b.y*q19b.y;
    const float cb = __cosf(b1s[19]), sb = __sinf(b1s[19]);
    const float2 gam1 = make_float2((s19a + s19b)*cb, (s19b - s19a)*sb);
    const float2 T04 = cadd(ipv[0], ipv[2]);
    const float2 T37 = cadd(ipv[1], ipv[3]);
    const float2 T15 = cadd(ipv[4], ipv[5]);
    const float2 h = cmul(gam1, T15);
    float2 acc = T04;
    const float sg1 = ((pp ^ qq) & 1) ? -1.f : 1.f;
    acc.x += sg1*T37.x; acc.y += sg1*T37.y;
    const float sgq = (qq & 1) ? -1.f : 1.f;
    acc.x += sgq*h.x; acc.y += sgq*h.y;
    const float sgp = (pp & 1) ? -1.f : 1.f;
    acc.x += sgp*h.x; acc.y -= sgp*h.y;   // + sgp * conj(h)
    q0s[pp*2 + qq] = make_float2(0.5f*acc.x, 0.5f*acc.y);
  } else if (t < 264) {
    const int ei = t - 260;               // (p,q) = (ei>>1, ei&1)
    const int pp = ei >> 1, qq = ei & 1;
    const int src = (pp == 0 && qq == 0) ? 0 : (pp == 1 && qq == 1) ? 2 : 1;
    float2 s = make_float2(0.f, 0.f);
    #pragma unroll
    for (int c = 0; c < 4; ++c) s = cadd(s, q3part[c][src]);
    if (pp == 1 && qq == 0) s.y = -s.y;   // conj for (1,0)
    q3s[pp*2 + qq] = s;
  }
  __syncthreads();

  // ---- phase 4: partial traces of block-0 rho ----------------------------
  if (t < 64) {
    const int i = t >> 3, j = t & 7;
    r012[t] = cadd(rho[(2*i)*16 + 2*j], rho[(2*i + 1)*16 + 2*j + 1]);
    r123[t] = cadd(rho[i*16 + j], rho[(i + 8)*16 + (j + 8)]);
  }
  if (t >= 64 && t < 80) {
    const int tt = t - 64;
    const int i = tt >> 2, j = tt & 3;
    float2 s1 = make_float2(0.f, 0.f), s2 = make_float2(0.f, 0.f);
    #pragma unroll
    for (int w = 0; w < 4; ++w) {
      s1 = cadd(s1, rho[(4*i + w)*16 + 4*j + w]);   // rho01
      s2 = cadd(s2, rho[(4*w + i)*16 + 4*w + j]);   // rho23
    }
    r01[tt] = s1;  r23[tt] = s2;
  }
  __syncthreads();

  if (t < 64) {
    const int i = t >> 3, j = t & 7;
    rk0[t] = cmul(q3s[(i >> 2)*2 + (j >> 2)], r01[(i & 3)*4 + (j & 3)]);
    rk3[t] = cmul(r23[(i >> 1)*4 + (j >> 1)], q0s[(i & 1)*2 + (j & 1)]);
  }
  __syncthreads();

  // ---- phase 5: Heisenberg expectations ----------------------------------
  if (t < 256) {
    const int k = t >> 6;
    const int idx = t & 63;
    const int i = idx >> 3, j = idx & 7;
    const float alpha = l2[2*k];
    const float beta1 = l2[2*((k + 15) & 15) + 1];
    const float beta2 = l2[2*k + 1];
    float ca, sa, cb1, sb1, cb2, sb2;
    __sincosf(alpha, &sa, &ca);
    __sincosf(beta1, &sb1, &cb1);
    __sincosf(beta2, &sb2, &cb2);
    float2 m1, m2;
    {
      const int xr = i ^ j;
      m1 = (xr == 0) ? make_float2( cb1*cb2, 0.f)
         : (xr == 3) ? make_float2( 0.f,    -cb1*sb2)
         : (xr == 6) ? make_float2( 0.f,    -sb1*cb2)
         : (xr == 5) ? make_float2(-sb1*sb2, 0.f)
         : make_float2(0.f, 0.f);
      const int xr2 = xr ^ 2;
      m2 = (xr2 == 0) ? make_float2( cb1*cb2, 0.f)
         : (xr2 == 3) ? make_float2( 0.f,    -cb1*sb2)
         : (xr2 == 6) ? make_float2( 0.f,    -sb1*cb2)
         : (xr2 == 5) ? make_float2(-sb1*sb2, 0.f)
         : make_float2(0.f, 0.f);
    }
    float2 O = make_float2(ca*m1.x + sa*m2.y, ca*m1.y - sa*m2.x);
    if ((i >> 1) & 1) { O.x = -O.x; O.y = -O.y; }
    const float2* rp = (k == 0) ? rk0 : (k == 1) ? r012 : (k == 2) ? r123 : rk3;
    const float2 rv = rp[j*8 + i];
    float contrib = O.x*rv.x - O.y*rv.y;
    for (int off = 32; off > 0; off >>= 1) contrib += __shfl_down(contrib, off);
    if (idx == 0) e[k] = contrib;
  }
  __syncthreads();

  // ---- phase 6: head + L2 normalize --------------------------------------
  float val = 0.f;
  if (t < 512) {
    val = hb[t] + e[0]*hw[4*t] + e[1]*hw[4*t + 1]
        + e[2]*hw[4*t + 2] + e[3]*hw[4*t + 3];
    float ss = val*val;
    for (int off = 32; off > 0; off >>= 1) ss += __shfl_down(ss, off);
    if ((t & 63) == 0) wsum[t >> 6] = ss;
  }
  __syncthreads();
  if (t == 0) {
    float s = 0.f;
    for (int w = 0; w < 8; ++w) s += wsum[w];
    nrm = fmaxf(sqrtf(s), 1e-12f);
  }
  __syncthreads();
  if (t < 512) out[(size_t)b*512 + t] = val / nrm;
}

extern "C" void kernel_launch(void* const* d_in, const int* in_sizes, int n_in,
                              void* d_out, int out_size, void* d_ws, size_t ws_size,
                              hipStream_t stream) {
  const float* x  = (const float*)d_in[0];  // (B,16,4,3)
  const float* pw = (const float*)d_in[1];  // (16,2)
  const float* lw = (const float*)d_in[2];  // (20,2)
  const float* l2 = (const float*)d_in[3];  // (16,2)
  const float* hw = (const float*)d_in[4];  // (512,4)
  const float* hb = (const float*)d_in[5];  // (512,)
  const int B = in_sizes[0] / (16*4*3);

  iqp_fused_kernel<<<B, 1024, 0, stream>>>(x, pw, lw, l2, hw, hb, (float*)d_out);
}

// Round 5
// 68.857 us; speedup vs baseline: 1.7502x; 1.0161x over previous
//
#include <hip/hip_runtime.h>
#include <math.h>

#define INV_SQRT2F 0.70710678118654752f

__device__ __forceinline__ float2 cmul(float2 a, float2 b) {
  return make_float2(a.x*b.x - a.y*b.y, a.x*b.y + a.y*b.x);
}
__device__ __forceinline__ float2 cmulc(float2 a, float2 b) { // a * conj(b)
  return make_float2(a.x*b.x + a.y*b.y, a.y*b.x - a.x*b.y);
}
__device__ __forceinline__ float2 cadd(float2 a, float2 b) {
  return make_float2(a.x + b.x, a.y + b.y);
}

// ---------------------------------------------------------------------------
// Fully fused kernel, one workgroup per batch row b, 1024 threads.
// R4-verified math. R5: phase-1 factored - the 4 per-thread m-chunks (j)
// differ only in qubits 1,2, so compute base = q0*q3..q8*q9*exp(-i phi_base/2)
// once and apply sqs[1][j1]*sqs[2][j0]*exp(-i phi_j/2) per j (2x fewer VALU
// ops in the longest phase).
// Blocks indexed kidx: 0->k0, 1->k1, 2->k3 (k=2 unused by reference).
// ---------------------------------------------------------------------------
__global__ __launch_bounds__(1024) void iqp_fused_kernel(
    const float* __restrict__ x,    // (B,16,4,3)
    const float* __restrict__ pw,   // (16,2)
    const float* __restrict__ lw,   // (20,2): a1,b1
    const float* __restrict__ l2,   // (16,2): a2,b2
    const float* __restrict__ hw,   // (512,4)
    const float* __restrict__ hb,   // (512,)
    float* __restrict__ out)        // (B,512)
{
  const int b = blockIdx.x;
  const int t = threadIdx.x;
  const int lane = t & 63;
  const int wid = t >> 6;

  __shared__ float2 sqs[3][20][2];   // per-kidx single-qubit states (a1 folded)
  __shared__ float  b1s[20];
  __shared__ float2 W[3][4][8][33];  // [kidx][class][chunk x][u], padded pitch
  __shared__ float2 D0[8][64];       // block-0 chunk Grams [pair][x*8+y]
  __shared__ float2 ipv[6];          // block-1 ips: 00,11,22,33,01,23
  __shared__ float2 q3part[4][3];    // block-3 per-class partials: 00,01,11
  __shared__ float2 rho[256];        // rho4 block 0
  __shared__ float2 r012[64], r123[64], rk0[64], rk3[64];
  __shared__ float2 r01[16], r23[16], q0s[4], q3s[4];
  __shared__ float  e[4];
  __shared__ float  wsum[8];
  __shared__ float  nrm;

  // ---- phase 0: single-qubit states for blocks {0,1,3} -------------------
  if (t < 60) {
    const int kidx = t / 20, q = t % 20;
    const int k = (kidx == 2) ? 3 : kidx;
    const int pch = 4*k + q/5;
    const int j = q % 5;
    float2 s0, s1;
    if (j < 4) {
      const float* xp = x + ((size_t)((b*16 + pch)*4 + j))*3;
      float cx, sx, cy, sy, cz, sz;
      __sincosf(0.5f*xp[0], &sx, &cx);
      __sincosf(0.5f*xp[1], &sy, &cy);
      __sincosf(0.5f*xp[2], &sz, &cz);
      float2 w0 = make_float2(cy*cx,  sy*sx);
      float2 w1 = make_float2(sy*cx, -cy*sx);
      w0 = cmul(make_float2(cz, -sz), w0);
      w1 = cmul(make_float2(cz,  sz), w1);
      s0 = make_float2((w0.x + w1.x)*INV_SQRT2F, (w0.y + w1.y)*INV_SQRT2F);
      s1 = make_float2((w0.x - w1.x)*INV_SQRT2F, (w0.y - w1.y)*INV_SQRT2F);
    } else {
      float cx, sx, cy, sy;
      __sincosf(0.5f*pw[2*pch], &sx, &cx);
      __sincosf(0.5f*pw[2*pch + 1], &sy, &cy);
      const float2 w0 = make_float2(cy*cx,  sy*sx);
      const float2 w1 = make_float2(sy*cx, -cy*sx);
      s0 = make_float2((w0.x + w1.x)*INV_SQRT2F, (w0.y + w1.y)*INV_SQRT2F);
      s1 = make_float2((w0.x - w1.x)*INV_SQRT2F, (w0.y - w1.y)*INV_SQRT2F);
    }
    float ca, sa;
    __sincosf(0.5f*lw[2*q], &sa, &ca);
    sqs[kidx][q][0] = cmul(s0, make_float2(ca, -sa));
    sqs[kidx][q][1] = cmul(s1, make_float2(ca,  sa));
    if (kidx == 0) b1s[q] = lw[2*q + 1];
  }
  __syncthreads();

  // ---- phase 1: F per (kidx, class) wave; WHT except for kidx==1 ---------
  // r = (b0<<9)|(m<<1)|b9, m = j*64+lane. Qubit bits: q0=b0, q9=b9,
  // q1=j>>1, q2=j&1, q3..q8 = lane bits 5..0.
  if (wid < 12) {
    const int kk = wid >> 2;       // kidx
    const int cls = wid & 3;
    const int b0 = cls & 1, b9 = cls >> 1;

    int bq[10];                    // qubit bits (q3..q8 from lane)
    bq[0] = b0; bq[9] = b9;
    #pragma unroll
    for (int q = 3; q < 9; ++q) bq[q] = (lane >> (8 - q)) & 1;

    // base = sqs[0][b0] * prod(q=3..8) * sqs[9][b9], with phi_base folded
    float2 base = sqs[kk][0][b0];
    #pragma unroll
    for (int q = 3; q < 9; ++q) base = cmul(base, sqs[kk][q][bq[q]]);
    base = cmul(base, sqs[kk][9][b9]);
    {
      float phi = 0.f;
      #pragma unroll
      for (int q = 3; q < 9; ++q) {
        const float zq  = 1.f - 2.f*(float)bq[q];
        const float zq1 = 1.f - 2.f*(float)bq[q + 1];
        phi += b1s[q]*zq*zq1;
      }
      float sp, cp;
      __sincosf(0.5f*phi, &sp, &cp);
      base = cmul(base, make_float2(cp, -sp));
    }
    const float2 t0 = cmul(base, sqs[kk][1][0]);   // q1 bit = 0
    const float2 t1 = cmul(base, sqs[kk][1][1]);   // q1 bit = 1
    const float z0 = 1.f - 2.f*(float)b0;
    const float z3 = 1.f - 2.f*(float)bq[3];

    float2 v[4];
    #pragma unroll
    for (int j = 0; j < 4; ++j) {
      const int j1 = j >> 1, j0 = j & 1;
      const float z1 = 1.f - 2.f*(float)j1;
      const float z2 = 1.f - 2.f*(float)j0;
      const float phij = b1s[0]*z0*z1 + b1s[1]*z1*z2 + b1s[2]*z2*z3;
      float sp, cp;
      __sincosf(0.5f*phij, &sp, &cp);
      v[j] = cmul(cmul(j1 ? t1 : t0, sqs[kk][2][j0]), make_float2(cp, -sp));
    }

    if (kk != 1) {  // WHT (block 1 only needs Parseval-invariant ips)
      {
        float2 a0 = v[0], a2 = v[2];
        v[0] = cadd(a0, a2); v[2] = make_float2(a0.x - a2.x, a0.y - a2.y);
        float2 a1 = v[1], a3 = v[3];
        v[1] = cadd(a1, a3); v[3] = make_float2(a1.x - a3.x, a1.y - a3.y);
        a0 = v[0]; a1 = v[1];
        v[0] = cadd(a0, a1); v[1] = make_float2(a0.x - a1.x, a0.y - a1.y);
        a2 = v[2]; a3 = v[3];
        v[2] = cadd(a2, a3); v[3] = make_float2(a2.x - a3.x, a2.y - a3.y);
      }
      #pragma unroll
      for (int mask = 1; mask <= 32; mask <<= 1) {
        #pragma unroll
        for (int j = 0; j < 4; ++j) {
          const float px = __shfl_xor(v[j].x, mask);
          const float py = __shfl_xor(v[j].y, mask);
          if (lane & mask) v[j] = make_float2(px - v[j].x, py - v[j].y);
          else             v[j] = make_float2(v[j].x + px, v[j].y + py);
        }
      }
    }
    // normalized-WHT scale (8 stages -> 2^-4) ONLY where the WHT ran;
    // block 1 stores raw F so <F,F> comes out unscaled (Parseval).
    const float scl = (kk == 1) ? 1.0f : 0.0625f;
    #pragma unroll
    for (int j = 0; j < 4; ++j) {
      const int m = j*64 + lane;
      W[kk][cls][m >> 5][m & 31] =
          make_float2(v[j].x*scl, v[j].y*scl);
    }
  }
  __syncthreads();

  // ---- phase 2: contractions ---------------------------------------------
  if (wid < 8) {
    // block 0: full chunk-Gram, 512 outputs, 1 per thread
    const int pr = t >> 6, idx = t & 63, xx = idx >> 3, yy = idx & 7;
    const int pa = pr >> 1;
    const int pb = (pr & 1) + ((pr >> 2) << 1);
    float2 acc = make_float2(0.f, 0.f);
    #pragma unroll 8
    for (int u = 0; u < 32; ++u)
      acc = cadd(acc, cmulc(W[0][pa][xx][u], W[0][pb][yy][u]));
    D0[pr][xx*8 + yy] = acc;
  } else if (wid < 12) {
    // block 1: inner products <F_pa, F_pb> over all 256 entries
    const int w4 = wid - 8;
    const int prl[6][2] = {{0,0},{1,1},{2,2},{3,3},{0,1},{2,3}};
    #pragma unroll
    for (int rep = 0; rep < 2; ++rep) {
      const int which = (rep == 0) ? w4 : w4 + 4;
      if (rep == 1 && w4 >= 2) break;
      const int pa = prl[which][0], pb = prl[which][1];
      float2 acc = make_float2(0.f, 0.f);
      #pragma unroll
      for (int jj = 0; jj < 4; ++jj) {
        const int m = jj*64 + lane;
        acc = cadd(acc, cmulc(W[1][pa][m >> 5][m & 31],
                              W[1][pb][m >> 5][m & 31]));
      }
      for (int off = 32; off > 0; off >>= 1) {
        acc.x += __shfl_down(acc.x, off);
        acc.y += __shfl_down(acc.y, off);
      }
      if (lane == 0) ipv[which] = acc;
    }
  } else {
    // block 3 (kidx 2): partial diagonal strips of diagonal pairs D_cc
    const int c = wid - 12;
    const int lo = lane >> 4;
    const int u0 = (lane & 15)*2;
    float2 a00 = make_float2(0.f, 0.f), a01 = a00, a11 = a00;
    #pragma unroll
    for (int du = 0; du < 2; ++du) {
      const float2 p0 = W[2][c][(lo << 1)    ][u0 + du];
      const float2 p1 = W[2][c][(lo << 1) | 1][u0 + du];
      a00 = cadd(a00, cmulc(p0, p0));
      a01 = cadd(a01, cmulc(p0, p1));
      a11 = cadd(a11, cmulc(p1, p1));
    }
    for (int off = 32; off > 0; off >>= 1) {
      a00.x += __shfl_down(a00.x, off); a00.y += __shfl_down(a00.y, off);
      a01.x += __shfl_down(a01.x, off); a01.y += __shfl_down(a01.y, off);
      a11.x += __shfl_down(a11.x, off); a11.y += __shfl_down(a11.y, off);
    }
    if (lane == 0) {
      q3part[c][0] = a00; q3part[c][1] = a01; q3part[c][2] = a11;
    }
  }
  __syncthreads();

  // ---- phase 3: assemble rho (block 0), q0 (block 1), q3 (block 3) -------
  if (t < 256) {
    const int i = t >> 4, j = t & 15;
    const int xy = (i & 7)*8 + (j & 7);
    const int si = i >> 3, sj = j >> 3;
    const float2 q19a = sqs[0][19][0], q19b = sqs[0][19][1];
    const float s19a = q19a.x*q19a.x + q19a.y*q19a.y;
    const float s19b = q19b.x*q19b.x + q19b.y*q19b.y;
    const float cb = __cosf(b1s[19]), sb = __sinf(b1s[19]);
    const float2 gam = make_float2((s19a + s19b)*cb, (s19b - s19a)*sb);
    float2 acc = cadd(D0[0][xy], D0[4][xy]);                 // (0,0)+(2,2)
    {
      const float2 t2 = cadd(D0[3][xy], D0[7][xy]);          // (1,1)+(3,3)
      const float sg = ((si ^ sj) & 1) ? -1.f : 1.f;
      acc.x += sg*t2.x; acc.y += sg*t2.y;
    }
    {
      float2 t3 = cadd(D0[1][xy], D0[5][xy]);                // (0,1)+(2,3)
      t3 = cmul(gam, t3);
      const float sg = (sj & 1) ? -1.f : 1.f;
      acc.x += sg*t3.x; acc.y += sg*t3.y;
    }
    {
      float2 t4 = cadd(D0[2][xy], D0[6][xy]);                // (1,0)+(3,2)
      t4 = cmulc(t4, gam);
      const float sg = (si & 1) ? -1.f : 1.f;
      acc.x += sg*t4.x; acc.y += sg*t4.y;
    }
    rho[t] = make_float2(0.5f*acc.x, 0.5f*acc.y);
  } else if (t < 260) {
    // q0[p][q] = 0.5( T04 + (-1)^{p^q} T37 + (-1)^q gam1 T15
    //                 + (-1)^p conj(gam1 T15) )
    const int pp = (t - 256) >> 1, qq = (t - 256) & 1;
    const float2 q19a = sqs[1][19][0], q19b = sqs[1][19][1];
    const float s19a = q19a.x*q19a.x + q19a.y*q19a.y;
    const float s19b = q19b.x*q19b.x + q19b.y*q19b.y;
    const float cb = __cosf(b1s[19]), sb = __sinf(b1s[19]);
    const float2 gam1 = make_float2((s19a + s19b)*cb, (s19b - s19a)*sb);
    const float2 T04 = cadd(ipv[0], ipv[2]);
    const float2 T37 = cadd(ipv[1], ipv[3]);
    const float2 T15 = cadd(ipv[4], ipv[5]);
    const float2 h = cmul(gam1, T15);
    float2 acc = T04;
    const float sg1 = ((pp ^ qq) & 1) ? -1.f : 1.f;
    acc.x += sg1*T37.x; acc.y += sg1*T37.y;
    const float sgq = (qq & 1) ? -1.f : 1.f;
    acc.x += sgq*h.x; acc.y += sgq*h.y;
    const float sgp = (pp & 1) ? -1.f : 1.f;
    acc.x += sgp*h.x; acc.y -= sgp*h.y;   // + sgp * conj(h)
    q0s[pp*2 + qq] = make_float2(0.5f*acc.x, 0.5f*acc.y);
  } else if (t < 264) {
    const int ei = t - 260;               // (p,q) = (ei>>1, ei&1)
    const int pp = ei >> 1, qq = ei & 1;
    const int src = (pp == 0 && qq == 0) ? 0 : (pp == 1 && qq == 1) ? 2 : 1;
    float2 s = make_float2(0.f, 0.f);
    #pragma unroll
    for (int c = 0; c < 4; ++c) s = cadd(s, q3part[c][src]);
    if (pp == 1 && qq == 0) s.y = -s.y;   // conj for (1,0)
    q3s[pp*2 + qq] = s;
  }
  __syncthreads();

  // ---- phase 4: partial traces of block-0 rho ----------------------------
  if (t < 64) {
    const int i = t >> 3, j = t & 7;
    r012[t] = cadd(rho[(2*i)*16 + 2*j], rho[(2*i + 1)*16 + 2*j + 1]);
    r123[t] = cadd(rho[i*16 + j], rho[(i + 8)*16 + (j + 8)]);
  }
  if (t >= 64 && t < 80) {
    const int tt = t - 64;
    const int i = tt >> 2, j = tt & 3;
    float2 s1 = make_float2(0.f, 0.f), s2 = make_float2(0.f, 0.f);
    #pragma unroll
    for (int w = 0; w < 4; ++w) {
      s1 = cadd(s1, rho[(4*i + w)*16 + 4*j + w]);   // rho01
      s2 = cadd(s2, rho[(4*w + i)*16 + 4*w + j]);   // rho23
    }
    r01[tt] = s1;  r23[tt] = s2;
  }
  __syncthreads();

  if (t < 64) {
    const int i = t >> 3, j = t & 7;
    rk0[t] = cmul(q3s[(i >> 2)*2 + (j >> 2)], r01[(i & 3)*4 + (j & 3)]);
    rk3[t] = cmul(r23[(i >> 1)*4 + (j >> 1)], q0s[(i & 1)*2 + (j & 1)]);
  }
  __syncthreads();

  // ---- phase 5: Heisenberg expectations ----------------------------------
  if (t < 256) {
    const int k = t >> 6;
    const int idx = t & 63;
    const int i = idx >> 3, j = idx & 7;
    const float alpha = l2[2*k];
    const float beta1 = l2[2*((k + 15) & 15) + 1];
    const float beta2 = l2[2*k + 1];
    float ca, sa, cb1, sb1, cb2, sb2;
    __sincosf(alpha, &sa, &ca);
    __sincosf(beta1, &sb1, &cb1);
    __sincosf(beta2, &sb2, &cb2);
    float2 m1, m2;
    {
      const int xr = i ^ j;
      m1 = (xr == 0) ? make_float2( cb1*cb2, 0.f)
         : (xr == 3) ? make_float2( 0.f,    -cb1*sb2)
         : (xr == 6) ? make_float2( 0.f,    -sb1*cb2)
         : (xr == 5) ? make_float2(-sb1*sb2, 0.f)
         : make_float2(0.f, 0.f);
      const int xr2 = xr ^ 2;
      m2 = (xr2 == 0) ? make_float2( cb1*cb2, 0.f)
         : (xr2 == 3) ? make_float2( 0.f,    -cb1*sb2)
         : (xr2 == 6) ? make_float2( 0.f,    -sb1*cb2)
         : (xr2 == 5) ? make_float2(-sb1*sb2, 0.f)
         : make_float2(0.f, 0.f);
    }
    float2 O = make_float2(ca*m1.x + sa*m2.y, ca*m1.y - sa*m2.x);
    if ((i >> 1) & 1) { O.x = -O.x; O.y = -O.y; }
    const float2* rp = (k == 0) ? rk0 : (k == 1) ? r012 : (k == 2) ? r123 : rk3;
    const float2 rv = rp[j*8 + i];
    float contrib = O.x*rv.x - O.y*rv.y;
    for (int off = 32; off > 0; off >>= 1) contrib += __shfl_down(contrib, off);
    if (idx == 0) e[k] = contrib;
  }
  __syncthreads();

  // ---- phase 6: head + L2 normalize --------------------------------------
  float val = 0.f;
  if (t < 512) {
    val = hb[t] + e[0]*hw[4*t] + e[1]*hw[4*t + 1]
        + e[2]*hw[4*t + 2] + e[3]*hw[4*t + 3];
    float ss = val*val;
    for (int off = 32; off > 0; off >>= 1) ss += __shfl_down(ss, off);
    if ((t & 63) == 0) wsum[t >> 6] = ss;
  }
  __syncthreads();
  if (t == 0) {
    float s = 0.f;
    for (int w = 0; w < 8; ++w) s += wsum[w];
    nrm = fmaxf(sqrtf(s), 1e-12f);
  }
  __syncthreads();
  if (t < 512) out[(size_t)b*512 + t] = val / nrm;
}

extern "C" void kernel_launch(void* const* d_in, const int* in_sizes, int n_in,
                              void* d_out, int out_size, void* d_ws, size_t ws_size,
                              hipStream_t stream) {
  const float* x  = (const float*)d_in[0];  // (B,16,4,3)
  const float* pw = (const float*)d_in[1];  // (16,2)
  const float* lw = (const float*)d_in[2];  // (20,2)
  const float* l2 = (const float*)d_in[3];  // (16,2)
  const float* hw = (const float*)d_in[4];  // (512,4)
  const float* hb = (const float*)d_in[5];  // (512,)
  const int B = in_sizes[0] / (16*4*3);

  iqp_fused_kernel<<<B, 1024, 0, stream>>>(x, pw, lw, l2, hw, hb, (float*)d_out);
}